// Round 3
// baseline (1556.490 us; speedup 1.0000x reference)
//
#include <hip/hip_runtime.h>

constexpr int kS = 1024;

typedef __attribute__((ext_vector_type(8))) short s16x8;
typedef __attribute__((ext_vector_type(4))) float f32x4;

__device__ __forceinline__ unsigned short f2bf(float x) {
    unsigned int u = __float_as_uint(x);
    u += 0x7FFFu + ((u >> 16) & 1u);
    return (unsigned short)(u >> 16);
}
__device__ __forceinline__ float bf2f(unsigned short h) {
    return __uint_as_float(((unsigned int)h) << 16);
}

// ---------------------------------------------------------------------------
// fp32 -> bf16 bulk convert, z selects one of up to 4 (src,dst) pairs
// ---------------------------------------------------------------------------
__global__ __launch_bounds__(256) void cvt_multi(
    const float* __restrict__ s0, const float* __restrict__ s1,
    const float* __restrict__ s2, const float* __restrict__ s3,
    unsigned short* __restrict__ d0, unsigned short* __restrict__ d1,
    unsigned short* __restrict__ d2, unsigned short* __restrict__ d3, int n)
{
    const int z = blockIdx.y;
    const float* s = z == 0 ? s0 : z == 1 ? s1 : z == 2 ? s2 : s3;
    unsigned short* d = z == 0 ? d0 : z == 1 ? d1 : z == 2 ? d2 : d3;
    const int i = (blockIdx.x * 256 + threadIdx.x) * 8;
    if (i >= n) return;
    const float4 a = *(const float4*)&s[i];
    const float4 b = *(const float4*)&s[i + 4];
    uint4 st;
    st.x = (unsigned int)f2bf(a.x) | ((unsigned int)f2bf(a.y) << 16);
    st.y = (unsigned int)f2bf(a.z) | ((unsigned int)f2bf(a.w) << 16);
    st.z = (unsigned int)f2bf(b.x) | ((unsigned int)f2bf(b.y) << 16);
    st.w = (unsigned int)f2bf(b.z) | ((unsigned int)f2bf(b.w) << 16);
    *(uint4*)&d[i] = st;
}

// ---------------------------------------------------------------------------
// bf16 MFMA GEMM (NT): C[m][n] = sum_k A[m][k]*B[n][k] + bias[n]
// tile 128x128, BK=64, 4 waves each 64x64 (4x4 of 16x16x32 frags).
// LDS chunk layout: 16B chunk at (row*8 + (ck ^ (row&7))) -> conflict-free
// b128 frag reads. Output fp32 (Cf) and/or bf16 (Cb).
// ---------------------------------------------------------------------------
__global__ __launch_bounds__(256, 2) void gemm_bf16(
    const unsigned short* __restrict__ A, const unsigned short* __restrict__ B,
    const float* __restrict__ bi0, const float* __restrict__ bi1, const float* __restrict__ bi2,
    float* __restrict__ Cf, unsigned short* __restrict__ Cb,
    int K, int N, long sA, long sB, long sC)
{
    __shared__ __align__(16) unsigned short As[128 * 64];
    __shared__ __align__(16) unsigned short Bs[128 * 64];
    const int t = threadIdx.x;
    const int z = blockIdx.z;
    const float* bi = (z == 0) ? bi0 : ((z == 1) ? bi1 : bi2);
    const int n0 = blockIdx.x * 128, m0 = blockIdx.y * 128;
    const int w = t >> 6, l = t & 63;
    const int wm = w >> 1, wn = w & 1;
    const long Ab = (long)z * sA, Bb = (long)z * sB, Cbse = (long)z * sC;

    f32x4 acc[4][4];
#pragma unroll
    for (int i = 0; i < 4; ++i)
#pragma unroll
        for (int j = 0; j < 4; ++j) acc[i][j] = (f32x4){0.f, 0.f, 0.f, 0.f};

    for (int k0 = 0; k0 < K; k0 += 64) {
#pragma unroll
        for (int i = 0; i < 4; ++i) {
            const int p = i * 256 + t;
            const int r = p >> 3, slot = p & 7;
            const int ck = slot ^ (r & 7);
            const s16x8 av = *(const s16x8*)&A[Ab + (long)(m0 + r) * K + k0 + ck * 8];
            const s16x8 bv = *(const s16x8*)&B[Bb + (long)(n0 + r) * K + k0 + ck * 8];
            *(s16x8*)&As[p * 8] = av;
            *(s16x8*)&Bs[p * 8] = bv;
        }
        __syncthreads();
#pragma unroll
        for (int s = 0; s < 2; ++s) {
            s16x8 af[4], bfr[4];
            const int g = l >> 4;
            const int ck = s * 4 + g;
#pragma unroll
            for (int mf = 0; mf < 4; ++mf) {
                const int row = wm * 64 + mf * 16 + (l & 15);
                af[mf] = *(const s16x8*)&As[(row * 8 + (ck ^ (row & 7))) * 8];
            }
#pragma unroll
            for (int nf = 0; nf < 4; ++nf) {
                const int col = wn * 64 + nf * 16 + (l & 15);
                bfr[nf] = *(const s16x8*)&Bs[(col * 8 + (ck ^ (col & 7))) * 8];
            }
#pragma unroll
            for (int mf = 0; mf < 4; ++mf)
#pragma unroll
                for (int nf = 0; nf < 4; ++nf)
                    acc[mf][nf] = __builtin_amdgcn_mfma_f32_16x16x32_bf16(
                        af[mf], bfr[nf], acc[mf][nf], 0, 0, 0);
        }
        __syncthreads();
    }

    float bv[4];
#pragma unroll
    for (int nf = 0; nf < 4; ++nf) bv[nf] = bi ? bi[n0 + wn * 64 + nf * 16 + (l & 15)] : 0.f;
#pragma unroll
    for (int mf = 0; mf < 4; ++mf)
#pragma unroll
        for (int r2 = 0; r2 < 4; ++r2) {
            const int row = m0 + wm * 64 + mf * 16 + (l >> 4) * 4 + r2;
#pragma unroll
            for (int nf = 0; nf < 4; ++nf) {
                const int col = n0 + wn * 64 + nf * 16 + (l & 15);
                const float v = acc[mf][nf][r2] + bv[nf];
                if (Cf) Cf[Cbse + (long)row * N + col] = v;
                if (Cb) Cb[Cbse + (long)row * N + col] = f2bf(v);
            }
        }
}

// ---------------------------------------------------------------------------
// qrel2T[b,s,j,m] = sum_n tw[n][m] * ( sum_d q[b,s,n,d] * W_rel[j][d] )
// one block per (b,s); q input is bf16
// ---------------------------------------------------------------------------
__global__ __launch_bounds__(256) void qrel2_kernel(
    const unsigned short* __restrict__ qproj, const float* __restrict__ W_rel,
    const float* __restrict__ tw, float* __restrict__ qrel2T)
{
    __shared__ float qrow[1024];     // [n][d]
    __shared__ float wrT[64 * 66];   // [d][j], padded stride 66
    __shared__ float twl[256];
    __shared__ float qr[16 * 65];    // [n][j]
    const int t = threadIdx.x;
    const long bs = blockIdx.x;
    {
        const ushort4 qv = *(const ushort4*)&qproj[bs * 1024 + t * 4];
        qrow[t * 4 + 0] = bf2f(qv.x);
        qrow[t * 4 + 1] = bf2f(qv.y);
        qrow[t * 4 + 2] = bf2f(qv.z);
        qrow[t * 4 + 3] = bf2f(qv.w);
    }
    for (int i = t; i < 65 * 64; i += 256) {
        const int j = i >> 6, d = i & 63;
        wrT[d * 66 + j] = W_rel[i];
    }
    twl[t] = tw[t];
    __syncthreads();
    for (int p = t; p < 16 * 65; p += 256) {
        const int n = p / 65, j = p % 65;
        float s = 0.f;
#pragma unroll 8
        for (int d = 0; d < 64; ++d) s = fmaf(qrow[n * 64 + d], wrT[d * 66 + j], s);
        qr[n * 65 + j] = s;
    }
    __syncthreads();
    for (int p = t; p < 16 * 65; p += 256) {
        const int m = p / 65, j = p % 65;
        float s = 0.f;
#pragma unroll
        for (int n = 0; n < 16; ++n) s = fmaf(twl[n * 16 + m], qr[n * 65 + j], s);
        qrel2T[bs * 1040 + j * 16 + m] = s;
    }
}

// ---------------------------------------------------------------------------
// Fused QK^T (all 16 heads, MFMA) + talking-heads mix + rel-pos + alibi +
// scale + mask -> scores, plus per-(row, 32k-chunk) softmax partials.
// grid (k/32, q/32, B), 256 threads = 4 waves; wave quadrant 16x16,
// all heads in acc regs (16 x f32x4). Heads staged in 2 passes of 8.
// ---------------------------------------------------------------------------
__global__ __launch_bounds__(256, 2) void qkmix(
    const unsigned short* __restrict__ qbp, const unsigned short* __restrict__ kbp,
    const float* __restrict__ qrel2T, const float* __restrict__ tw,
    const unsigned char* __restrict__ mask,
    const int* __restrict__ qpos, const int* __restrict__ kpos,
    float* __restrict__ scores, float2* __restrict__ statp)
{
    __shared__ __align__(16) unsigned short qls[32 * 64 * 8];  // 32KB
    __shared__ __align__(16) unsigned short kls[32 * 64 * 8];  // 32KB
    __shared__ float twl[256];
    __shared__ float cmL[16];
    __shared__ int qposs[32], kposs[32];
    __shared__ float2 statL[2][32][16];
    const int t = threadIdx.x;
    const int k0 = blockIdx.x * 32, q0 = blockIdx.y * 32, b = blockIdx.z;
    const int w = t >> 6, l = t & 63;
    const int qoff = (w >> 1) * 16, koff = (w & 1) * 16;

    twl[t] = tw[t];
    if (t < 32) qposs[t] = qpos[b * kS + q0 + t];
    if (t >= 64 && t < 96) kposs[t - 64] = kpos[b * kS + (t - 64) + k0];
    __syncthreads();
    if (t < 16) {  // cm[m] = sum_n slopes[n]*tw[n][m], slopes[n]=start^(n+1)
        float s = 0.f, cur = 0.70710678118654752f;
        for (int n = 0; n < 16; ++n) { s = fmaf(cur, twl[n * 16 + t], s); cur *= 0.70710678118654752f; }
        cmL[t] = s;
    }

    f32x4 acc[16];
#pragma unroll
    for (int n = 0; n < 16; ++n) acc[n] = (f32x4){0.f, 0.f, 0.f, 0.f};

#pragma unroll
    for (int pass = 0; pass < 2; ++pass) {
        __syncthreads();  // protect LDS reuse (pass 1) / cover shared init (pass 0)
#pragma unroll
        for (int i = 0; i < 8; ++i) {
            const int p = i * 256 + t;
            const int r = p >> 6, slot = p & 63;
            const int nd = slot ^ (r & 7);
            *(s16x8*)&qls[p * 8] =
                *(const s16x8*)&qbp[((long)(b * kS + q0 + r)) * 1024 + pass * 512 + nd * 8];
            *(s16x8*)&kls[p * 8] =
                *(const s16x8*)&kbp[((long)(b * kS + k0 + r)) * 1024 + pass * 512 + nd * 8];
        }
        __syncthreads();
#pragma unroll
        for (int nl = 0; nl < 8; ++nl) {
            const int g = l >> 4;
            const int row = qoff + (l & 15);
            const int col = koff + (l & 15);
            const s16x8 a0 = *(const s16x8*)&qls[(row * 64 + ((nl * 8 + g) ^ (row & 7))) * 8];
            const s16x8 a1 = *(const s16x8*)&qls[(row * 64 + ((nl * 8 + 4 + g) ^ (row & 7))) * 8];
            const s16x8 b0 = *(const s16x8*)&kls[(col * 64 + ((nl * 8 + g) ^ (col & 7))) * 8];
            const s16x8 b1 = *(const s16x8*)&kls[(col * 64 + ((nl * 8 + 4 + g) ^ (col & 7))) * 8];
            acc[pass * 8 + nl] = __builtin_amdgcn_mfma_f32_16x16x32_bf16(a0, b0, acc[pass * 8 + nl], 0, 0, 0);
            acc[pass * 8 + nl] = __builtin_amdgcn_mfma_f32_16x16x32_bf16(a1, b1, acc[pass * 8 + nl], 0, 0, 0);
        }
    }

    // mix + stats, fully in-register per lane (4 points: rows qoff+4g+r, col koff+cl)
    const int g = l >> 4, cl = l & 15;
    const int kg_loc = koff + cl;
    const int kp = kposs[kg_loc];
    const int kgl = k0 + kg_loc;
#pragma unroll
    for (int r = 0; r < 4; ++r) {
        const int row_l = qoff + g * 4 + r;
        const int row_g = q0 + row_l;
        const int rel = qposs[row_l] - kp;
        const int idx = (rel < -32 ? -32 : (rel > 32 ? 32 : rel)) + 32;
        const float ab = fabsf((float)rel);
        const bool msk = mask[((long)b * kS + row_g) * kS + kgl] != 0;
        const float* q2p = &qrel2T[((long)(b * kS + row_g) * 65 + idx) * 16];
        float q2v[16];
        *(float4*)&q2v[0] = *(const float4*)&q2p[0];
        *(float4*)&q2v[4] = *(const float4*)&q2p[4];
        *(float4*)&q2v[8] = *(const float4*)&q2p[8];
        *(float4*)&q2v[12] = *(const float4*)&q2p[12];
        float val[16];
#pragma unroll
        for (int m = 0; m < 16; ++m) {
            float s = 0.f;
#pragma unroll
            for (int n = 0; n < 16; ++n) s = fmaf(acc[n][r], twl[n * 16 + m], s);
            float v = (s + q2v[m] + ab * cmL[m]) * 0.125f;
            val[m] = msk ? -10000.f : v;
            scores[((long)(b * 16 + m) * kS + row_g) * kS + kgl] = val[m];
        }
        float smx = 0.f, ssm = 0.f;
#pragma unroll
        for (int m = 0; m < 16; ++m) {
            float mx = val[m];
            mx = fmaxf(mx, __shfl_xor(mx, 1, 16));
            mx = fmaxf(mx, __shfl_xor(mx, 2, 16));
            mx = fmaxf(mx, __shfl_xor(mx, 4, 16));
            mx = fmaxf(mx, __shfl_xor(mx, 8, 16));
            float e = __expf(val[m] - mx);
            e += __shfl_xor(e, 1, 16);
            e += __shfl_xor(e, 2, 16);
            e += __shfl_xor(e, 4, 16);
            e += __shfl_xor(e, 8, 16);
            if (cl == m) { smx = mx; ssm = e; }
        }
        statL[w & 1][row_l][cl] = make_float2(smx, ssm);
    }
    __syncthreads();
    for (int e = t; e < 512; e += 256) {
        const int row = e >> 4, m = e & 15;
        const float2 s0 = statL[0][row][m], s1 = statL[1][row][m];
        const float M = fmaxf(s0.x, s1.x);
        const float sm = s0.y * __expf(s0.x - M) + s1.y * __expf(s1.x - M);
        statp[((long)(b * 16 + m) * kS + q0 + row) * 32 + blockIdx.x] = make_float2(M, sm);
    }
}

// ---------------------------------------------------------------------------
// combine 32 partials -> (M, 1/l) per (b,h,q) row
// ---------------------------------------------------------------------------
__global__ __launch_bounds__(256) void stats_final(
    const float2* __restrict__ statp, float2* __restrict__ stats)
{
    const int rr = blockIdx.x * 256 + threadIdx.x;  // 0..32767
    const float2* p = statp + (long)rr * 32;
    float M = -1e30f;
#pragma unroll 8
    for (int i = 0; i < 32; ++i) M = fmaxf(M, p[i].x);
    float l = 0.f;
#pragma unroll 8
    for (int i = 0; i < 32; ++i) l += p[i].y * __expf(p[i].x - M);
    l = fmaxf(l, 1e-30f);
    stats[rr] = make_float2(M, 1.f / l);
}

// ---------------------------------------------------------------------------
// attn + PV + rel-pos value term.  grid (qt=16, h=16, b=2), 256 threads.
// (round-1 kernel; edits: bf16 V input, bf16 head_out output)
// ---------------------------------------------------------------------------
__global__ __launch_bounds__(256) void attn_pv(
    const float* __restrict__ scores, float* __restrict__ attn,
    const unsigned short* __restrict__ vproj, const float* __restrict__ wrel_g,
    const float2* __restrict__ stats, unsigned short* __restrict__ head_out)
{
    __shared__ float atT[64][68];     // transposed attn tile [k][q]
    __shared__ float vs[64][64];      // v tile [k][d]  (aliased as pv partial later)
    __shared__ float amid[64][64];    // middle-bucket gather [q][j]
    __shared__ float red_lo[64][16];
    __shared__ float red_hi[64][16];
    __shared__ float MR[64][2];
    __shared__ float wrl[65 * 64];

    const int t = threadIdx.x;
    const int q0 = blockIdx.x * 64;
    const int h = blockIdx.y;
    const int b = blockIdx.z;

    if (t < 64) {
        const float2 s2 = stats[(long)(b * 16 + h) * kS + q0 + t];
        MR[t][0] = s2.x; MR[t][1] = s2.y;
    }
    for (int i = t; i < 65 * 64; i += 256) wrl[i] = wrel_g[i];
    {
        float* amf = &amid[0][0];
        for (int i = t; i < 64 * 64; i += 256) amf[i] = 0.f;
    }

    const int g = t >> 7;            // k-half group for PV
    const int u = t & 127;
    const int txd = u & 15, tyq = u >> 4;
    const int qs = tyq * 8, ds = txd * 4;
    const int korg = g * 32;
    const int arow = t >> 4;         // 0..15
    const int akq = (t & 15) * 4;    // 0..60

    float acc[8][4];
#pragma unroll
    for (int i = 0; i < 8; ++i)
#pragma unroll
        for (int j = 0; j < 4; ++j) acc[i][j] = 0.f;
    float slo[4] = {0.f, 0.f, 0.f, 0.f};
    float shi[4] = {0.f, 0.f, 0.f, 0.f};

    const long scb = (long)(b * 16 + h) * kS;
    for (int kt = 0; kt < 16; ++kt) {
        const int k0 = kt * 64;
        __syncthreads();
        // stage v tile (bf16 -> f32)
#pragma unroll
        for (int r = 0; r < 4; ++r) {
            const int krow = arow + 16 * r;
            const ushort4 vv = *(const ushort4*)&vproj[(((long)(b * kS + k0 + krow)) * 16 + h) * 64 + akq];
            vs[krow][akq + 0] = bf2f(vv.x);
            vs[krow][akq + 1] = bf2f(vv.y);
            vs[krow][akq + 2] = bf2f(vv.z);
            vs[krow][akq + 3] = bf2f(vv.w);
        }
        // attn phase
#pragma unroll
        for (int r = 0; r < 4; ++r) {
            const int qrow = arow + 16 * r;
            const int qg = q0 + qrow;
            const long off = (scb + qg) * kS + k0 + akq;
            const float4 s4 = *(const float4*)&scores[off];
            const float M = MR[qrow][0], R = MR[qrow][1];
            const float a0 = expf(s4.x - M) * R;
            const float a1 = expf(s4.y - M) * R;
            const float a2 = expf(s4.z - M) * R;
            const float a3 = expf(s4.w - M) * R;
            const float4 a4o = make_float4(a0, a1, a2, a3);
            *(float4*)&attn[off] = a4o;
            atT[akq + 0][qrow] = a0;
            atT[akq + 1][qrow] = a1;
            atT[akq + 2][qrow] = a2;
            atT[akq + 3][qrow] = a3;
            const float av[4] = {a0, a1, a2, a3};
#pragma unroll
            for (int j = 0; j < 4; ++j) {
                const int kg = k0 + akq + j;
                const int jj = qg - kg + 32;
                if (jj >= 1 && jj <= 63) amid[qrow][jj] = av[j];
                else if (jj >= 64) slo[r] += av[j];
                else shi[r] += av[j];
            }
        }
        __syncthreads();
        // PV accumulate (each group half the k-tile)
#pragma unroll 4
        for (int kk = 0; kk < 32; ++kk) {
            const int k = korg + kk;
            float a8[8], v4[4];
            *(float4*)&a8[0] = *(const float4*)&atT[k][qs];
            *(float4*)&a8[4] = *(const float4*)&atT[k][qs + 4];
            *(float4*)&v4[0] = *(const float4*)&vs[k][ds];
#pragma unroll
            for (int i = 0; i < 8; ++i)
#pragma unroll
                for (int j = 0; j < 4; ++j)
                    acc[i][j] = fmaf(a8[i], v4[j], acc[i][j]);
        }
    }
    __syncthreads();
    float* pvp = &vs[0][0];
    if (g == 1) {
#pragma unroll
        for (int i = 0; i < 8; ++i)
#pragma unroll
            for (int j = 0; j < 4; ++j) pvp[u * 32 + i * 4 + j] = acc[i][j];
    }
#pragma unroll
    for (int r = 0; r < 4; ++r) {
        const int qrow = arow + 16 * r;
        red_lo[qrow][t & 15] = slo[r];
        red_hi[qrow][t & 15] = shi[r];
    }
    __syncthreads();
    if (g == 0) {
#pragma unroll
        for (int i = 0; i < 8; ++i)
#pragma unroll
            for (int j = 0; j < 4; ++j) acc[i][j] += pvp[u * 32 + i * 4 + j];
#pragma unroll
        for (int i = 0; i < 8; ++i) {
            const int qrow = qs + i;
            float Sl = 0.f, Sh = 0.f;
#pragma unroll
            for (int lq = 0; lq < 16; ++lq) { Sl += red_lo[qrow][lq]; Sh += red_hi[qrow][lq]; }
#pragma unroll
            for (int j = 0; j < 4; ++j)
                acc[i][j] += Sh * wrl[ds + j] + Sl * wrl[64 * 64 + ds + j];
        }
        for (int jj = 1; jj < 64; ++jj) {
            float wv[4];
            *(float4*)&wv[0] = *(const float4*)&wrl[jj * 64 + ds];
#pragma unroll
            for (int i = 0; i < 8; ++i) {
                const float am = amid[qs + i][jj];
#pragma unroll
                for (int j = 0; j < 4; ++j) acc[i][j] = fmaf(am, wv[j], acc[i][j]);
            }
        }
#pragma unroll
        for (int i = 0; i < 8; ++i) {
            ushort4 h4;
            h4.x = f2bf(acc[i][0]); h4.y = f2bf(acc[i][1]);
            h4.z = f2bf(acc[i][2]); h4.w = f2bf(acc[i][3]);
            *(ushort4*)&head_out[(((long)(b * kS + q0 + qs + i)) * 16 + h) * 64 + ds] = h4;
        }
    }
}

// ---------------------------------------------------------------------------
extern "C" void kernel_launch(void* const* d_in, const int* in_sizes, int n_in,
                              void* d_out, int out_size, void* d_ws, size_t ws_size,
                              hipStream_t stream)
{
    const float* q_in = (const float*)d_in[0];
    const float* k_in = (const float*)d_in[1];
    const float* v_in = (const float*)d_in[2];
    const unsigned char* mask = (const unsigned char*)d_in[3];
    const int* qpos = (const int*)d_in[4];
    const int* kpos = (const int*)d_in[5];
    const float* W_q = (const float*)d_in[6];
    const float* b_q = (const float*)d_in[7];
    const float* W_k = (const float*)d_in[8];
    const float* b_k = (const float*)d_in[9];
    const float* W_v = (const float*)d_in[10];
    const float* b_v = (const float*)d_in[11];
    const float* W_o = (const float*)d_in[12];
    const float* b_o = (const float*)d_in[13];
    const float* W_rel = (const float*)d_in[14];
    const float* tw = (const float*)d_in[15];

    unsigned char* W = (unsigned char*)d_ws;
    unsigned short* in_bf  = (unsigned short*)W;                    // 3 x 2M bf16 = 12,582,912 B
    unsigned short* w_bf   = (unsigned short*)(W + 12582912);       // 4 x 1M bf16 =  8,388,608 B
    unsigned short* qkv_bf = (unsigned short*)(W + 20971520);       // 3 x 2M bf16 = 12,582,912 B
    float*          qrel2T = (float*)(W + 33554432);                // 2,129,920 f  =  8,519,680 B
    float2*         statp  = (float2*)W;                            // aliases in_bf (dead after proj)
    float2*         stats  = (float2*)(W + 42074112);               //    262,144 B
    unsigned short* hout   = (unsigned short*)(W + 42336256);       //  4,194,304 B  (total ~46.5MB)

    float* out = (float*)d_out;
    float* attn = out + 2097152;
    float* scores = attn + 33554432;

    const dim3 blk(256, 1, 1);
    // fp32 -> bf16 converts
    cvt_multi<<<dim3(1024, 3), blk, 0, stream>>>(q_in, k_in, v_in, nullptr,
        in_bf, in_bf + 2097152, in_bf + 4194304, nullptr, 2097152);
    cvt_multi<<<dim3(512, 4), blk, 0, stream>>>(W_q, W_k, W_v, W_o,
        w_bf, w_bf + 1048576, w_bf + 2097152, w_bf + 3145728, 1048576);
    // Q/K/V projections (one fused MFMA launch, z=0..2) -> bf16
    gemm_bf16<<<dim3(8, 16, 3), blk, 0, stream>>>(in_bf, w_bf, b_q, b_k, b_v,
        nullptr, qkv_bf, 1024, 1024, 2097152L, 1048576L, 2097152L);
    // relative-pos projection (talking-heads pre-mixed), [b,s,j,m] layout
    qrel2_kernel<<<dim3(2048, 1, 1), blk, 0, stream>>>(qkv_bf, W_rel, tw, qrel2T);
    // fused QK^T + mix + scores + softmax partials
    qkmix<<<dim3(32, 32, 2), blk, 0, stream>>>(qkv_bf, qkv_bf + 2097152,
        qrel2T, tw, mask, qpos, kpos, scores, statp);
    stats_final<<<dim3(128, 1, 1), blk, 0, stream>>>(statp, stats);
    // attn + PV + positional value term
    attn_pv<<<dim3(16, 16, 2), blk, 0, stream>>>(scores, attn,
        qkv_bf + 4194304, W_rel, stats, hout);
    // output projection (MFMA) -> fp32 out
    gemm_bf16<<<dim3(8, 16, 1), blk, 0, stream>>>(hout, w_bf + 3145728,
        b_o, b_o, b_o, out, nullptr, 1024, 1024, 0L, 0L, 0L);
}

// Round 5
// 1496.918 us; speedup vs baseline: 1.0398x; 1.0398x over previous
//
#include <hip/hip_runtime.h>

constexpr int kS = 1024;

typedef __attribute__((ext_vector_type(8))) short s16x8;
typedef __attribute__((ext_vector_type(4))) float f32x4;

__device__ __forceinline__ unsigned short f2bf(float x) {
    unsigned int u = __float_as_uint(x);
    u += 0x7FFFu + ((u >> 16) & 1u);
    return (unsigned short)(u >> 16);
}
__device__ __forceinline__ float bf2f(unsigned short h) {
    return __uint_as_float(((unsigned int)h) << 16);
}

// ---------------------------------------------------------------------------
// fp32 -> bf16 bulk convert, z selects one of up to 4 (src,dst) pairs
// ---------------------------------------------------------------------------
__global__ __launch_bounds__(256) void cvt_multi(
    const float* __restrict__ s0, const float* __restrict__ s1,
    const float* __restrict__ s2, const float* __restrict__ s3,
    unsigned short* __restrict__ d0, unsigned short* __restrict__ d1,
    unsigned short* __restrict__ d2, unsigned short* __restrict__ d3, int n)
{
    const int z = blockIdx.y;
    const float* s = z == 0 ? s0 : z == 1 ? s1 : z == 2 ? s2 : s3;
    unsigned short* d = z == 0 ? d0 : z == 1 ? d1 : z == 2 ? d2 : d3;
    const int i = (blockIdx.x * 256 + threadIdx.x) * 8;
    if (i >= n) return;
    const float4 a = *(const float4*)&s[i];
    const float4 b = *(const float4*)&s[i + 4];
    uint4 st;
    st.x = (unsigned int)f2bf(a.x) | ((unsigned int)f2bf(a.y) << 16);
    st.y = (unsigned int)f2bf(a.z) | ((unsigned int)f2bf(a.w) << 16);
    st.z = (unsigned int)f2bf(b.x) | ((unsigned int)f2bf(b.y) << 16);
    st.w = (unsigned int)f2bf(b.z) | ((unsigned int)f2bf(b.w) << 16);
    *(uint4*)&d[i] = st;
}

// ---------------------------------------------------------------------------
// bf16 MFMA GEMM (NT): C[m][n] = sum_k A[m][k]*B[n][k] + bias[n]
// tile 128x128, BK=64, 4 waves each 64x64 (4x4 of 16x16x32 frags).
// ---------------------------------------------------------------------------
__global__ __launch_bounds__(256, 2) void gemm_bf16(
    const unsigned short* __restrict__ A, const unsigned short* __restrict__ B,
    const float* __restrict__ bi0, const float* __restrict__ bi1, const float* __restrict__ bi2,
    float* __restrict__ Cf, unsigned short* __restrict__ Cb,
    int K, int N, long sA, long sB, long sC)
{
    __shared__ __align__(16) unsigned short As[128 * 64];
    __shared__ __align__(16) unsigned short Bs[128 * 64];
    const int t = threadIdx.x;
    const int z = blockIdx.z;
    const float* bi = (z == 0) ? bi0 : ((z == 1) ? bi1 : bi2);
    const int n0 = blockIdx.x * 128, m0 = blockIdx.y * 128;
    const int w = t >> 6, l = t & 63;
    const int wm = w >> 1, wn = w & 1;
    const long Ab = (long)z * sA, Bb = (long)z * sB, Cbse = (long)z * sC;

    f32x4 acc[4][4];
#pragma unroll
    for (int i = 0; i < 4; ++i)
#pragma unroll
        for (int j = 0; j < 4; ++j) acc[i][j] = (f32x4){0.f, 0.f, 0.f, 0.f};

    for (int k0 = 0; k0 < K; k0 += 64) {
#pragma unroll
        for (int i = 0; i < 4; ++i) {
            const int p = i * 256 + t;
            const int r = p >> 3, slot = p & 7;
            const int ck = slot ^ (r & 7);
            const s16x8 av = *(const s16x8*)&A[Ab + (long)(m0 + r) * K + k0 + ck * 8];
            const s16x8 bv = *(const s16x8*)&B[Bb + (long)(n0 + r) * K + k0 + ck * 8];
            *(s16x8*)&As[p * 8] = av;
            *(s16x8*)&Bs[p * 8] = bv;
        }
        __syncthreads();
#pragma unroll
        for (int s = 0; s < 2; ++s) {
            s16x8 af[4], bfr[4];
            const int g = l >> 4;
            const int ck = s * 4 + g;
#pragma unroll
            for (int mf = 0; mf < 4; ++mf) {
                const int row = wm * 64 + mf * 16 + (l & 15);
                af[mf] = *(const s16x8*)&As[(row * 8 + (ck ^ (row & 7))) * 8];
            }
#pragma unroll
            for (int nf = 0; nf < 4; ++nf) {
                const int col = wn * 64 + nf * 16 + (l & 15);
                bfr[nf] = *(const s16x8*)&Bs[(col * 8 + (ck ^ (col & 7))) * 8];
            }
#pragma unroll
            for (int mf = 0; mf < 4; ++mf)
#pragma unroll
                for (int nf = 0; nf < 4; ++nf)
                    acc[mf][nf] = __builtin_amdgcn_mfma_f32_16x16x32_bf16(
                        af[mf], bfr[nf], acc[mf][nf], 0, 0, 0);
        }
        __syncthreads();
    }

    float bv[4];
#pragma unroll
    for (int nf = 0; nf < 4; ++nf) bv[nf] = bi ? bi[n0 + wn * 64 + nf * 16 + (l & 15)] : 0.f;
#pragma unroll
    for (int mf = 0; mf < 4; ++mf)
#pragma unroll
        for (int r2 = 0; r2 < 4; ++r2) {
            const int row = m0 + wm * 64 + mf * 16 + (l >> 4) * 4 + r2;
#pragma unroll
            for (int nf = 0; nf < 4; ++nf) {
                const int col = n0 + wn * 64 + nf * 16 + (l & 15);
                const float v = acc[mf][nf][r2] + bv[nf];
                if (Cf) Cf[Cbse + (long)row * N + col] = v;
                if (Cb) Cb[Cbse + (long)row * N + col] = f2bf(v);
            }
        }
}

// ---------------------------------------------------------------------------
// qrel2T[b,s,j,m] = sum_n tw[n][m] * ( sum_d q[b,s,n,d] * W_rel[j][d] )
// ---------------------------------------------------------------------------
__global__ __launch_bounds__(256) void qrel2_kernel(
    const unsigned short* __restrict__ qproj, const float* __restrict__ W_rel,
    const float* __restrict__ tw, float* __restrict__ qrel2T)
{
    __shared__ float qrow[1024];
    __shared__ float wrT[64 * 66];
    __shared__ float twl[256];
    __shared__ float qr[16 * 65];
    const int t = threadIdx.x;
    const long bs = blockIdx.x;
    {
        const ushort4 qv = *(const ushort4*)&qproj[bs * 1024 + t * 4];
        qrow[t * 4 + 0] = bf2f(qv.x);
        qrow[t * 4 + 1] = bf2f(qv.y);
        qrow[t * 4 + 2] = bf2f(qv.z);
        qrow[t * 4 + 3] = bf2f(qv.w);
    }
    for (int i = t; i < 65 * 64; i += 256) {
        const int j = i >> 6, d = i & 63;
        wrT[d * 66 + j] = W_rel[i];
    }
    twl[t] = tw[t];
    __syncthreads();
    for (int p = t; p < 16 * 65; p += 256) {
        const int n = p / 65, j = p % 65;
        float s = 0.f;
#pragma unroll 8
        for (int d = 0; d < 64; ++d) s = fmaf(qrow[n * 64 + d], wrT[d * 66 + j], s);
        qr[n * 65 + j] = s;
    }
    __syncthreads();
    for (int p = t; p < 16 * 65; p += 256) {
        const int m = p / 65, j = p % 65;
        float s = 0.f;
#pragma unroll
        for (int n = 0; n < 16; ++n) s = fmaf(twl[n * 16 + m], qr[n * 65 + j], s);
        qrel2T[bs * 1040 + j * 16 + m] = s;
    }
}

// ---------------------------------------------------------------------------
// Fused QK^T (16 heads, MFMA) + talking-heads mix + rel-pos + alibi + mask
// -> scores via LDS transpose (full-line float4 writes), + softmax partials
// (per-block contiguous statp). grid (k/32, q/32, B), 4 waves.
// ---------------------------------------------------------------------------
__global__ __launch_bounds__(256, 2) void qkmix(
    const unsigned short* __restrict__ qbp, const unsigned short* __restrict__ kbp,
    const float* __restrict__ qrel2T, const float* __restrict__ tw,
    const unsigned char* __restrict__ mask,
    const int* __restrict__ qpos, const int* __restrict__ kpos,
    float* __restrict__ scores, float2* __restrict__ statp)
{
    // stg aliased: phase A = q/k staging (2x32KB); phase B/C = scoreT
    // (8 planes x [32 rows][36 pad cols] f32 = 36864B)
    __shared__ __align__(16) unsigned short stg[2][16384];
    __shared__ float twl[256];
    __shared__ float cmL[16];
    __shared__ int qposs[32], kposs[32];
    __shared__ float2 statL[2][32][16];
    unsigned short* qls = &stg[0][0];
    unsigned short* kls = &stg[1][0];
    float* scoreT = (float*)&stg[0][0];

    const int t = threadIdx.x;
    const int k0 = blockIdx.x * 32, q0 = blockIdx.y * 32, b = blockIdx.z;
    const int w = t >> 6, l = t & 63;
    const int qoff = (w >> 1) * 16, koff = (w & 1) * 16;

    twl[t] = tw[t];
    if (t < 32) qposs[t] = qpos[b * kS + q0 + t];
    if (t >= 64 && t < 96) kposs[t - 64] = kpos[b * kS + (t - 64) + k0];
    __syncthreads();
    if (t < 16) {  // cm[m] = sum_n slopes[n]*tw[n][m], slopes[n]=start^(n+1)
        float s = 0.f, cur = 0.70710678118654752f;
        for (int n = 0; n < 16; ++n) { s = fmaf(cur, twl[n * 16 + t], s); cur *= 0.70710678118654752f; }
        cmL[t] = s;
    }

    f32x4 acc[16];
#pragma unroll
    for (int n = 0; n < 16; ++n) acc[n] = (f32x4){0.f, 0.f, 0.f, 0.f};

#pragma unroll
    for (int pass = 0; pass < 2; ++pass) {
        __syncthreads();
#pragma unroll
        for (int i = 0; i < 8; ++i) {
            const int p = i * 256 + t;
            const int r = p >> 6, slot = p & 63;
            const int nd = slot ^ (r & 7);
            *(s16x8*)&qls[p * 8] =
                *(const s16x8*)&qbp[((long)(b * kS + q0 + r)) * 1024 + pass * 512 + nd * 8];
            *(s16x8*)&kls[p * 8] =
                *(const s16x8*)&kbp[((long)(b * kS + k0 + r)) * 1024 + pass * 512 + nd * 8];
        }
        __syncthreads();
#pragma unroll
        for (int nl = 0; nl < 8; ++nl) {
            const int g = l >> 4;
            const int row = qoff + (l & 15);
            const int col = koff + (l & 15);
            const s16x8 a0 = *(const s16x8*)&qls[(row * 64 + ((nl * 8 + g) ^ (row & 7))) * 8];
            const s16x8 a1 = *(const s16x8*)&qls[(row * 64 + ((nl * 8 + 4 + g) ^ (row & 7))) * 8];
            const s16x8 b0 = *(const s16x8*)&kls[(col * 64 + ((nl * 8 + g) ^ (col & 7))) * 8];
            const s16x8 b1 = *(const s16x8*)&kls[(col * 64 + ((nl * 8 + 4 + g) ^ (col & 7))) * 8];
            acc[pass * 8 + nl] = __builtin_amdgcn_mfma_f32_16x16x32_bf16(a0, b0, acc[pass * 8 + nl], 0, 0, 0);
            acc[pass * 8 + nl] = __builtin_amdgcn_mfma_f32_16x16x32_bf16(a1, b1, acc[pass * 8 + nl], 0, 0, 0);
        }
    }
    __syncthreads();  // staging dead; scoreT alias live from here

    // phase B: mix + stats in-register; planes 0-7 -> scoreT, 8-15 -> vsave
    const int g = l >> 4, cl = l & 15;
    const int kg_loc = koff + cl;
    const int kp = kposs[kg_loc];
    const int kgl = k0 + kg_loc;
    float vsave[4][8];
#pragma unroll
    for (int r = 0; r < 4; ++r) {
        const int row_l = qoff + g * 4 + r;
        const int row_g = q0 + row_l;
        const int rel = qposs[row_l] - kp;
        const int idx = (rel < -32 ? -32 : (rel > 32 ? 32 : rel)) + 32;
        const float ab = fabsf((float)rel);
        const bool msk = mask[((long)b * kS + row_g) * kS + kgl] != 0;
        const float* q2p = &qrel2T[((long)(b * kS + row_g) * 65 + idx) * 16];
        float q2v[16];
        *(float4*)&q2v[0] = *(const float4*)&q2p[0];
        *(float4*)&q2v[4] = *(const float4*)&q2p[4];
        *(float4*)&q2v[8] = *(const float4*)&q2p[8];
        *(float4*)&q2v[12] = *(const float4*)&q2p[12];
        float val[16];
#pragma unroll
        for (int m = 0; m < 16; ++m) {
            float s = 0.f;
#pragma unroll
            for (int n = 0; n < 16; ++n) s = fmaf(acc[n][r], twl[n * 16 + m], s);
            float v = (s + q2v[m] + ab * cmL[m]) * 0.125f;
            val[m] = msk ? -10000.f : v;
        }
#pragma unroll
        for (int m = 0; m < 8; ++m) scoreT[m * 1152 + row_l * 36 + kg_loc] = val[m];
#pragma unroll
        for (int m = 0; m < 8; ++m) vsave[r][m] = val[m + 8];

        float smx = 0.f, ssm = 0.f;
#pragma unroll
        for (int m = 0; m < 16; ++m) {
            float mx = val[m];
            mx = fmaxf(mx, __shfl_xor(mx, 1, 16));
            mx = fmaxf(mx, __shfl_xor(mx, 2, 16));
            mx = fmaxf(mx, __shfl_xor(mx, 4, 16));
            mx = fmaxf(mx, __shfl_xor(mx, 8, 16));
            float e = __expf(val[m] - mx);
            e += __shfl_xor(e, 1, 16);
            e += __shfl_xor(e, 2, 16);
            e += __shfl_xor(e, 4, 16);
            e += __shfl_xor(e, 8, 16);
            if (cl == m) { smx = mx; ssm = e; }
        }
        statL[w & 1][row_l][cl] = make_float2(smx, ssm);
    }

    // phase C: cooperative full-line write-out, 8 planes per half
    const int row_o = t >> 3, cg = (t & 7) * 4;
    __syncthreads();
#pragma unroll
    for (int mh = 0; mh < 8; ++mh) {
        const float* sp = &scoreT[mh * 1152 + row_o * 36 + cg];
        const float4 v = make_float4(sp[0], sp[1], sp[2], sp[3]);
        *(float4*)&scores[(((long)(b * 16 + mh)) << 20) + ((long)(q0 + row_o) << 10) + k0 + cg] = v;
    }
    __syncthreads();
#pragma unroll
    for (int r = 0; r < 4; ++r) {
        const int row_l = qoff + g * 4 + r;
#pragma unroll
        for (int m = 0; m < 8; ++m) scoreT[m * 1152 + row_l * 36 + kg_loc] = vsave[r][m];
    }
    __syncthreads();
#pragma unroll
    for (int mh = 0; mh < 8; ++mh) {
        const float* sp = &scoreT[mh * 1152 + row_o * 36 + cg];
        const float4 v = make_float4(sp[0], sp[1], sp[2], sp[3]);
        *(float4*)&scores[(((long)(b * 16 + 8 + mh)) << 20) + ((long)(q0 + row_o) << 10) + k0 + cg] = v;
    }

    // per-block contiguous stat partials (4KB run)
    const long blockID = ((long)b * 32 + blockIdx.y) * 32 + blockIdx.x;
    for (int e = t; e < 512; e += 256) {
        const int row = e >> 4, m = e & 15;
        const float2 s0 = statL[0][row][m], s1 = statL[1][row][m];
        const float M = fmaxf(s0.x, s1.x);
        const float sm = s0.y * __expf(s0.x - M) + s1.y * __expf(s1.x - M);
        statp[blockID * 512 + e] = make_float2(M, sm);
    }
}

// ---------------------------------------------------------------------------
// combine 32 k-tile partials -> (M, 1/l). one block per (b, q-tile of 32);
// reads whole 4KB partial regions fully coalesced.
// ---------------------------------------------------------------------------
__global__ __launch_bounds__(256) void stats_final(
    const float2* __restrict__ statp, float2* __restrict__ stats)
{
    const int b = blockIdx.x >> 5, q0 = blockIdx.x & 31;
    const int t = threadIdx.x;
    const long base = ((long)b * 32 + q0) * 32;
    float M0 = -1e30f, M1 = -1e30f, l0 = 0.f, l1 = 0.f;
    for (int x = 0; x < 32; ++x) {
        const float4 v = *(const float4*)&statp[(base + x) * 512 + 2 * t];
        const float nM0 = fmaxf(M0, v.x);
        l0 = l0 * __expf(M0 - nM0) + v.y * __expf(v.x - nM0); M0 = nM0;
        const float nM1 = fmaxf(M1, v.z);
        l1 = l1 * __expf(M1 - nM1) + v.w * __expf(v.z - nM1); M1 = nM1;
    }
    {
        const int p = 2 * t, row = p >> 4, m = p & 15;
        stats[((long)(b * 16 + m)) * 1024 + q0 * 32 + row] =
            make_float2(M0, 1.f / fmaxf(l0, 1e-30f));
    }
    {
        const int p = 2 * t + 1, row = p >> 4, m = p & 15;
        stats[((long)(b * 16 + m)) * 1024 + q0 * 32 + row] =
            make_float2(M1, 1.f / fmaxf(l1, 1e-30f));
    }
}

// ---------------------------------------------------------------------------
// attn + PV + rel-pos value term.  grid (qt=16, h=16, b=2), 256 threads.
// ---------------------------------------------------------------------------
__global__ __launch_bounds__(256) void attn_pv(
    const float* __restrict__ scores, float* __restrict__ attn,
    const unsigned short* __restrict__ vproj, const float* __restrict__ wrel_g,
    const float2* __restrict__ stats, unsigned short* __restrict__ head_out)
{
    __shared__ float atT[64][68];
    __shared__ float vs[64][64];
    __shared__ float amid[64][64];
    __shared__ float red_lo[64][16];
    __shared__ float red_hi[64][16];
    __shared__ float MR[64][2];
    __shared__ float wrl[65 * 64];

    const int t = threadIdx.x;
    const int q0 = blockIdx.x * 64;
    const int h = blockIdx.y;
    const int b = blockIdx.z;

    if (t < 64) {
        const float2 s2 = stats[(long)(b * 16 + h) * kS + q0 + t];
        MR[t][0] = s2.x; MR[t][1] = s2.y;
    }
    for (int i = t; i < 65 * 64; i += 256) wrl[i] = wrel_g[i];
    {
        float* amf = &amid[0][0];
        for (int i = t; i < 64 * 64; i += 256) amf[i] = 0.f;
    }

    const int g = t >> 7;
    const int u = t & 127;
    const int txd = u & 15, tyq = u >> 4;
    const int qs = tyq * 8, ds = txd * 4;
    const int korg = g * 32;
    const int arow = t >> 4;
    const int akq = (t & 15) * 4;

    float acc[8][4];
#pragma unroll
    for (int i = 0; i < 8; ++i)
#pragma unroll
        for (int j = 0; j < 4; ++j) acc[i][j] = 0.f;
    float slo[4] = {0.f, 0.f, 0.f, 0.f};
    float shi[4] = {0.f, 0.f, 0.f, 0.f};

    const long scb = (long)(b * 16 + h) * kS;
    for (int kt = 0; kt < 16; ++kt) {
        const int k0 = kt * 64;
        __syncthreads();
#pragma unroll
        for (int r = 0; r < 4; ++r) {
            const int krow = arow + 16 * r;
            const ushort4 vv = *(const ushort4*)&vproj[(((long)(b * kS + k0 + krow)) * 16 + h) * 64 + akq];
            vs[krow][akq + 0] = bf2f(vv.x);
            vs[krow][akq + 1] = bf2f(vv.y);
            vs[krow][akq + 2] = bf2f(vv.z);
            vs[krow][akq + 3] = bf2f(vv.w);
        }
#pragma unroll
        for (int r = 0; r < 4; ++r) {
            const int qrow = arow + 16 * r;
            const int qg = q0 + qrow;
            const long off = (scb + qg) * kS + k0 + akq;
            const float4 s4 = *(const float4*)&scores[off];
            const float M = MR[qrow][0], R = MR[qrow][1];
            const float a0 = __expf(s4.x - M) * R;
            const float a1 = __expf(s4.y - M) * R;
            const float a2 = __expf(s4.z - M) * R;
            const float a3 = __expf(s4.w - M) * R;
            *(float4*)&attn[off] = make_float4(a0, a1, a2, a3);
            atT[akq + 0][qrow] = a0;
            atT[akq + 1][qrow] = a1;
            atT[akq + 2][qrow] = a2;
            atT[akq + 3][qrow] = a3;
            const float av[4] = {a0, a1, a2, a3};
#pragma unroll
            for (int j = 0; j < 4; ++j) {
                const int kg = k0 + akq + j;
                const int jj = qg - kg + 32;
                if (jj >= 1 && jj <= 63) amid[qrow][jj] = av[j];
                else if (jj >= 64) slo[r] += av[j];
                else shi[r] += av[j];
            }
        }
        __syncthreads();
#pragma unroll 4
        for (int kk = 0; kk < 32; ++kk) {
            const int k = korg + kk;
            float a8[8], v4[4];
            *(float4*)&a8[0] = *(const float4*)&atT[k][qs];
            *(float4*)&a8[4] = *(const float4*)&atT[k][qs + 4];
            *(float4*)&v4[0] = *(const float4*)&vs[k][ds];
#pragma unroll
            for (int i = 0; i < 8; ++i)
#pragma unroll
                for (int j = 0; j < 4; ++j)
                    acc[i][j] = fmaf(a8[i], v4[j], acc[i][j]);
        }
    }
    __syncthreads();
    float* pvp = &vs[0][0];
    if (g == 1) {
#pragma unroll
        for (int i = 0; i < 8; ++i)
#pragma unroll
            for (int j = 0; j < 4; ++j) pvp[u * 32 + i * 4 + j] = acc[i][j];
    }
#pragma unroll
    for (int r = 0; r < 4; ++r) {
        const int qrow = arow + 16 * r;
        red_lo[qrow][t & 15] = slo[r];
        red_hi[qrow][t & 15] = shi[r];
    }
    __syncthreads();
    if (g == 0) {
#pragma unroll
        for (int i = 0; i < 8; ++i)
#pragma unroll
            for (int j = 0; j < 4; ++j) acc[i][j] += pvp[u * 32 + i * 4 + j];
#pragma unroll
        for (int i = 0; i < 8; ++i) {
            const int qrow = qs + i;
            float Sl = 0.f, Sh = 0.f;
#pragma unroll
            for (int lq = 0; lq < 16; ++lq) { Sl += red_lo[qrow][lq]; Sh += red_hi[qrow][lq]; }
#pragma unroll
            for (int j = 0; j < 4; ++j)
                acc[i][j] += Sh * wrl[ds + j] + Sl * wrl[64 * 64 + ds + j];
        }
        for (int jj = 1; jj < 64; ++jj) {
            float wv[4];
            *(float4*)&wv[0] = *(const float4*)&wrl[jj * 64 + ds];
#pragma unroll
            for (int i = 0; i < 8; ++i) {
                const float am = amid[qs + i][jj];
#pragma unroll
                for (int j = 0; j < 4; ++j) acc[i][j] = fmaf(am, wv[j], acc[i][j]);
            }
        }
#pragma unroll
        for (int i = 0; i < 8; ++i) {
            ushort4 h4;
            h4.x = f2bf(acc[i][0]); h4.y = f2bf(acc[i][1]);
            h4.z = f2bf(acc[i][2]); h4.w = f2bf(acc[i][3]);
            *(ushort4*)&head_out[(((long)(b * kS + q0 + qs + i)) * 16 + h) * 64 + ds] = h4;
        }
    }
}

// ---------------------------------------------------------------------------
extern "C" void kernel_launch(void* const* d_in, const int* in_sizes, int n_in,
                              void* d_out, int out_size, void* d_ws, size_t ws_size,
                              hipStream_t stream)
{
    const float* q_in = (const float*)d_in[0];
    const float* k_in = (const float*)d_in[1];
    const float* v_in = (const float*)d_in[2];
    const unsigned char* mask = (const unsigned char*)d_in[3];
    const int* qpos = (const int*)d_in[4];
    const int* kpos = (const int*)d_in[5];
    const float* W_q = (const float*)d_in[6];
    const float* b_q = (const float*)d_in[7];
    const float* W_k = (const float*)d_in[8];
    const float* b_k = (const float*)d_in[9];
    const float* W_v = (const float*)d_in[10];
    const float* b_v = (const float*)d_in[11];
    const float* W_o = (const float*)d_in[12];
    const float* b_o = (const float*)d_in[13];
    const float* W_rel = (const float*)d_in[14];
    const float* tw = (const float*)d_in[15];

    unsigned char* W = (unsigned char*)d_ws;
    unsigned short* in_bf  = (unsigned short*)W;                    // 12,582,912 B
    unsigned short* w_bf   = (unsigned short*)(W + 12582912);       //  8,388,608 B
    unsigned short* qkv_bf = (unsigned short*)(W + 20971520);       // 12,582,912 B
    float*          qrel2T = (float*)(W + 33554432);                //  8,519,680 B
    float2*         statp  = (float2*)W;                            // 8MB, aliases in_bf (dead after proj)
    float2*         stats  = (float2*)(W + 42074112);               //    262,144 B
    unsigned short* hout   = (unsigned short*)(W + 42336256);       //  4,194,304 B

    float* out = (float*)d_out;
    float* attn = out + 2097152;
    float* scores = attn + 33554432;

    const dim3 blk(256, 1, 1);
    cvt_multi<<<dim3(1024, 3), blk, 0, stream>>>(q_in, k_in, v_in, nullptr,
        in_bf, in_bf + 2097152, in_bf + 4194304, nullptr, 2097152);
    cvt_multi<<<dim3(512, 4), blk, 0, stream>>>(W_q, W_k, W_v, W_o,
        w_bf, w_bf + 1048576, w_bf + 2097152, w_bf + 3145728, 1048576);
    gemm_bf16<<<dim3(8, 16, 3), blk, 0, stream>>>(in_bf, w_bf, b_q, b_k, b_v,
        nullptr, qkv_bf, 1024, 1024, 2097152L, 1048576L, 2097152L);
    qrel2_kernel<<<dim3(2048, 1, 1), blk, 0, stream>>>(qkv_bf, W_rel, tw, qrel2T);
    qkmix<<<dim3(32, 32, 2), blk, 0, stream>>>(qkv_bf, qkv_bf + 2097152,
        qrel2T, tw, mask, qpos, kpos, scores, statp);
    stats_final<<<dim3(64, 1, 1), blk, 0, stream>>>(statp, stats);
    attn_pv<<<dim3(16, 16, 2), blk, 0, stream>>>(scores, attn,
        qkv_bf + 4194304, W_rel, stats, hout);
    gemm_bf16<<<dim3(8, 16, 1), blk, 0, stream>>>(hout, w_bf + 3145728,
        b_o, b_o, b_o, out, nullptr, 1024, 1024, 0L, 0L, 0L);
}